// Round 2
// baseline (384.944 us; speedup 1.0000x reference)
//
#include <hip/hip_runtime.h>

#define NNODES 100000
#define NEDGES 1600000
#define INDIM 128
#define OUTD 32
#define HEADS 4
#define EDIM 32
#define NET 8
#define NEG 0.2f
#define CAP 64           // per-node bucket capacity (Poisson(16): P(>64) ~ 1e-20)
#define SB 1600          // scatter blocks (first in grid: latency overlaps gemm)
#define GB2 782          // gemm blocks: ceil(100000/128)

typedef unsigned short u16;
typedef unsigned int u32;
typedef __attribute__((ext_vector_type(8))) short bf16x8;
typedef __attribute__((ext_vector_type(8))) unsigned short ushort8;
typedef __attribute__((ext_vector_type(4))) float f32x4;

__device__ __forceinline__ float bf2f(u16 u){ return __uint_as_float(((u32)u) << 16); }
__device__ __forceinline__ u16 f2bf(float f){
  u32 x = __float_as_uint(f);
  return (u16)((x + 0x7fffu + ((x >> 16) & 1u)) >> 16);   // RNE
}

// ---------------------------------------------------------------------------
// k_prep: block 0 -> he_t;  blocks 1..128 -> Wt transpose+cast;  all -> zero cnt
// ---------------------------------------------------------------------------
__global__ void k_prep(const float* __restrict__ edge_emb, const float* __restrict__ Wr,
                       const float* __restrict__ a_e, const float* __restrict__ W,
                       const float* __restrict__ res_w,
                       float* __restrict__ he_t, u16* __restrict__ Wt,
                       int* __restrict__ cnt){
  const int b = blockIdx.x, tid = threadIdx.x;
  for (int i = b * 256 + tid; i < NNODES; i += gridDim.x * 256) cnt[i] = 0;

  if (b == 0){
    __shared__ float sc[NET * 128];
    for (int idx = tid; idx < NET * 128; idx += 256){
      int t = idx >> 7, o = idx & 127;
      float s = 0.f;
      #pragma unroll
      for (int e = 0; e < EDIM; ++e)
        s += edge_emb[t * EDIM + e] * Wr[t * EDIM * 128 + e * 128 + o];
      sc[idx] = s * a_e[o];
    }
    __syncthreads();
    if (tid < NET * HEADS){
      int t = tid >> 2, h = tid & 3;
      float s = 0.f;
      #pragma unroll
      for (int d = 0; d < EDIM; ++d) s += sc[t * 128 + h * EDIM + d];
      he_t[tid] = s;
    }
  } else {
    int idx = (b - 1) * 256 + tid;     // 128 blocks cover 256*128
    int n = idx >> 7, k = idx & 127;
    float v = (n < 128) ? W[k * 128 + n] : res_w[k * 128 + (n - 128)];
    Wt[idx] = f2bf(v);
  }
}

// ---------------------------------------------------------------------------
// k_main: blocks [0,SB): bucket scatter rtp[c*CAP+pos] = row | etype<<17
//         blocks [SB,SB+GB2): MFMA GEMM, 128 rows x 256 cols, Wt in LDS.
//   gemm cols 0-127 -> emb bf16 + h_l/h_r; cols 128-255 -> d_out fp32 residual.
// ---------------------------------------------------------------------------
__global__ __launch_bounds__(256) void k_main(
    const float* __restrict__ hmat, const u16* __restrict__ Wt,
    const float* __restrict__ res_b, const float* __restrict__ a_l,
    const float* __restrict__ a_r, u16* __restrict__ emb, float* __restrict__ outres,
    float* __restrict__ h_l, float* __restrict__ h_r,
    const int* __restrict__ row, const int* __restrict__ col,
    const int* __restrict__ et, int* __restrict__ cnt, int* __restrict__ rtp){
  __shared__ u16 Wl[128 * 136];        // 34.8 KB (2-way bank spread = free)
  const int tid = threadIdx.x;

  if (blockIdx.x < SB){                // ---- scatter part ----
    for (int e = blockIdx.x * 256 + tid; e < NEDGES; e += SB * 256){
      int c = col[e];
      int pos = atomicAdd(&cnt[c], 1);
      if (pos < CAP) rtp[c * CAP + pos] = row[e] | (et[e] << 17);
    }
    return;
  }

  // ---- GEMM part ----
  const int gb = blockIdx.x - SB;
  const int wid = tid >> 6, lane = tid & 63;
  const int m0 = gb * 128 + wid * 32;
  const int mcol = lane & 15, quad = lane >> 4;

  // A fragments: 2 row-tiles x 4 k-steps, fp32 -> bf16 in-register
  bf16x8 A[2][4];
  #pragma unroll
  for (int mt = 0; mt < 2; ++mt){
    int r = m0 + mt * 16 + mcol;
    int rc = r < NNODES ? r : NNODES - 1;
    const float* hrow = &hmat[rc * 128 + quad * 8];
    #pragma unroll
    for (int ks = 0; ks < 4; ++ks){
      float4 a0 = *(const float4*)&hrow[ks * 32];
      float4 a1 = *(const float4*)&hrow[ks * 32 + 4];
      A[mt][ks][0] = (short)f2bf(a0.x); A[mt][ks][1] = (short)f2bf(a0.y);
      A[mt][ks][2] = (short)f2bf(a0.z); A[mt][ks][3] = (short)f2bf(a0.w);
      A[mt][ks][4] = (short)f2bf(a1.x); A[mt][ks][5] = (short)f2bf(a1.y);
      A[mt][ks][6] = (short)f2bf(a1.z); A[mt][ks][7] = (short)f2bf(a1.w);
    }
  }

  float pl[2][4] = {}, pr[2][4] = {};
  #pragma unroll
  for (int phase = 0; phase < 2; ++phase){
    if (phase) __syncthreads();
    // stage 128 rows of Wt (32 KB) -> LDS, 8 x 16B per thread
    #pragma unroll
    for (int j = 0; j < 8; ++j){
      int cid = tid + j * 256;          // 2048 chunks of ushort8
      int rowL = cid >> 4, k8 = cid & 15;
      *(uint4*)&Wl[rowL * 136 + k8 * 8] =
          *(const uint4*)&Wt[(phase * 128 + rowL) * 128 + k8 * 8];
    }
    __syncthreads();

    #pragma unroll
    for (int ntl = 0; ntl < 8; ++ntl){
      bf16x8 B[4];
      const u16* bp = &Wl[(ntl * 16 + mcol) * 136 + quad * 8];
      #pragma unroll
      for (int ks = 0; ks < 4; ++ks) B[ks] = *(const bf16x8*)&bp[ks * 32];

      f32x4 acc[2] = {{0.f,0.f,0.f,0.f},{0.f,0.f,0.f,0.f}};
      #pragma unroll
      for (int ks = 0; ks < 4; ++ks){
        acc[0] = __builtin_amdgcn_mfma_f32_16x16x32_bf16(A[0][ks], B[ks], acc[0], 0, 0, 0);
        acc[1] = __builtin_amdgcn_mfma_f32_16x16x32_bf16(A[1][ks], B[ks], acc[1], 0, 0, 0);
      }

      const int c = ntl * 16 + mcol;      // column within the 128-col phase
      if (phase == 0){
        float alc = a_l[c], arc = a_r[c];
        #pragma unroll
        for (int mt = 0; mt < 2; ++mt){
          #pragma unroll
          for (int reg = 0; reg < 4; ++reg){
            int rw = m0 + mt * 16 + quad * 4 + reg;
            if (rw < NNODES) emb[rw * 128 + c] = f2bf(acc[mt][reg]);
            pl[mt][reg] += alc * acc[mt][reg];
            pr[mt][reg] += arc * acc[mt][reg];
          }
        }
        if (ntl & 1){            // head h = ntl>>1 complete
          int h = ntl >> 1;
          #pragma unroll
          for (int mt = 0; mt < 2; ++mt){
            #pragma unroll
            for (int reg = 0; reg < 4; ++reg){
              float s0 = pl[mt][reg], s1 = pr[mt][reg];
              #pragma unroll
              for (int off = 1; off < 16; off <<= 1){
                s0 += __shfl_xor(s0, off, 64);
                s1 += __shfl_xor(s1, off, 64);
              }
              int rw = m0 + mt * 16 + quad * 4 + reg;
              if (mcol == 0 && rw < NNODES){
                h_l[rw * 4 + h] = s0;
                h_r[rw * 4 + h] = s1;
              }
              pl[mt][reg] = 0.f; pr[mt][reg] = 0.f;
            }
          }
        }
      } else {
        float rb = res_b[c];
        #pragma unroll
        for (int mt = 0; mt < 2; ++mt){
          #pragma unroll
          for (int reg = 0; reg < 4; ++reg){
            int rw = m0 + mt * 16 + quad * 4 + reg;
            if (rw < NNODES) outres[rw * 128 + c] = acc[mt][reg] + rb;
          }
        }
      }
    }
  }
}

// ---------------------------------------------------------------------------
// k_nodeagg: one wave per node.
// Prologue (lane = slot, parallel): w[4] = exp(leaky(h_l[r]+h_r[n]+he[t]))
//   -> LDS (fp32), r -> LDS.  he table read straight from global (L1-resident).
// Main loop: QUARTER-wave per edge (16 lanes x ushort8 = 256B row), 4 edges
//   per step, 2 steps unrolled -> 8 edges / iter, 2 independent dwordx4
//   gathers in flight per wave (MLP), 4x fewer iterations than half-wave.
// Fused normalize + permute + fp32 residual (preloaded in out) + ELU.
// ---------------------------------------------------------------------------
__global__ __launch_bounds__(256) void k_nodeagg(const int* __restrict__ cnt,
    const int* __restrict__ rtp, const float* __restrict__ h_l,
    const float* __restrict__ h_r, const float* __restrict__ he_t_g,
    const u16* __restrict__ emb, float* __restrict__ out){
  __shared__ float wl[4][CAP][4];      // [wave][slot][head], fp32
  __shared__ int   rl[4][CAP];

  const int wid = threadIdx.x >> 6;
  const int n = blockIdx.x * 4 + wid;            // grid*4 == NNODES exactly
  const int lane = threadIdx.x & 63;
  int deg = cnt[n]; if (deg > CAP) deg = CAP;
  const int base = n * CAP;

  // ---- prologue: per-slot weights, all slots in parallel ----
  {
    bool v = lane < deg;
    int rt = rtp[base + (v ? lane : 0)];
    int r = rt & 0x1FFFF, t = (rt >> 17) & 7;
    float4 hl = *(const float4*)&h_l[r * 4];
    float4 hr = *(const float4*)&h_r[n * 4];
    float4 he = *(const float4*)&he_t_g[t * 4];
    float x0 = hl.x + hr.x + he.x; x0 = x0 > 0.f ? x0 : NEG * x0;
    float x1 = hl.y + hr.y + he.y; x1 = x1 > 0.f ? x1 : NEG * x1;
    float x2 = hl.z + hr.z + he.z; x2 = x2 > 0.f ? x2 : NEG * x2;
    float x3 = hl.w + hr.w + he.w; x3 = x3 > 0.f ? x3 : NEG * x3;
    float4 w4 = make_float4(__expf(x0), __expf(x1), __expf(x2), __expf(x3));
    *(float4*)&wl[wid][lane][0] = w4;
    rl[wid][lane] = r;
  }
  __syncthreads();

  const int q = lane >> 4;             // quarter 0..3 -> edge i+q
  const int L = lane & 15;             // dims L*8 .. L*8+7 (emb layout [head][32])
  const int h = L >> 2;                // head of this lane's 8 dims

  float acc[8] = {0.f,0.f,0.f,0.f,0.f,0.f,0.f,0.f};
  float ds = 0.f;
  for (int i = 0; i < deg; i += 8){
    int i0 = i + q, i1 = i + 4 + q;
    bool v0 = i0 < deg, v1 = i1 < deg;
    int ii0 = v0 ? i0 : 0, ii1 = v1 ? i1 : 0;
    int r0 = rl[wid][ii0];                       // LDS broadcast
    int r1 = rl[wid][ii1];
    float w0 = v0 ? wl[wid][ii0][h] : 0.f;       // LDS broadcast
    float w1 = v1 ? wl[wid][ii1][h] : 0.f;
    ushort8 u0 = *(const ushort8*)&emb[r0 * 128 + L * 8];
    ushort8 u1 = *(const ushort8*)&emb[r1 * 128 + L * 8];
    #pragma unroll
    for (int k = 0; k < 8; ++k) acc[k] += w0 * bf2f((u16)u0[k]);
    ds += w0;
    #pragma unroll
    for (int k = 0; k < 8; ++k) acc[k] += w1 * bf2f((u16)u1[k]);
    ds += w1;
  }

  // combine the 4 quarters: lanes L, L+16, L+32, L+48 hold partials of same dims
  #pragma unroll
  for (int k = 0; k < 8; ++k){
    acc[k] += __shfl_xor(acc[k], 16, 64);
    acc[k] += __shfl_xor(acc[k], 32, 64);
  }
  ds += __shfl_xor(ds, 16, 64);
  ds += __shfl_xor(ds, 32, 64);

  if (q == 0){
    float inv = (deg > 0) ? 1.f / ds : 0.f;
    // dim j = L*8+k -> out offset n*128 + (j&31)*4 + head
    //              = n*128 + (L&3)*32 + k*4 + (L>>2)
    int ob = n * 128 + (L & 3) * 32 + (L >> 2);
    #pragma unroll
    for (int k = 0; k < 8; ++k){
      int o = ob + k * 4;
      float v = acc[k] * inv + out[o];
      out[o] = v > 0.f ? v : (__expf(v) - 1.f);
    }
  }
}

// ---------------------------------------------------------------------------
extern "C" void kernel_launch(void* const* d_in, const int* in_sizes, int n_in,
                              void* d_out, int out_size, void* d_ws, size_t ws_size,
                              hipStream_t stream){
  const float* hmat     = (const float*)d_in[0];
  const int*   row      = (const int*)d_in[1];
  const int*   col      = (const int*)d_in[2];
  const int*   et       = (const int*)d_in[3];
  const float* edge_emb = (const float*)d_in[4];
  const float* W        = (const float*)d_in[5];
  const float* Wr       = (const float*)d_in[6];
  const float* a_l      = (const float*)d_in[7];
  const float* a_r      = (const float*)d_in[8];
  const float* a_e      = (const float*)d_in[9];
  const float* res_w    = (const float*)d_in[10];
  const float* res_b    = (const float*)d_in[11];
  float* out = (float*)d_out;

  char* ws = (char*)d_ws;
  // he_t 256 | Wt 64K | h_l 1.6M | h_r 1.6M | cnt 400K | rtp 25.6M |
  // emb(bf16) 25.6M    (~55 MB)
  float* he_t   = (float*)(ws);
  u16*   Wt     = (u16*)  (ws + 256);
  float* h_l    = (float*)(ws + 65792);
  float* h_r    = (float*)(ws + 1665792);
  int*   cnt    = (int*)  (ws + 3265792);
  int*   rtp    = (int*)  (ws + 3665792);
  u16*   emb    = (u16*)  (ws + 29265792);

  hipLaunchKernelGGL(k_prep, dim3(129), dim3(256), 0, stream,
                     edge_emb, Wr, a_e, W, res_w, he_t, Wt, cnt);
  hipLaunchKernelGGL(k_main, dim3(SB + GB2), dim3(256), 0, stream,
                     hmat, Wt, res_b, a_l, a_r, emb, out, h_l, h_r,
                     row, col, et, cnt, rtp);
  hipLaunchKernelGGL(k_nodeagg, dim3(NNODES / 4), dim3(256), 0, stream,
                     cnt, rtp, h_l, h_r, he_t, emb, out);
}

// Round 3
// 364.467 us; speedup vs baseline: 1.0562x; 1.0562x over previous
//
#include <hip/hip_runtime.h>

#define NNODES 100000
#define NEDGES 1600000
#define INDIM 128
#define OUTD 32
#define HEADS 4
#define EDIM 32
#define NET 8
#define NEG 0.2f
#define CAP 64           // per-node bucket capacity (Poisson(16): P(>64) ~ 1e-20)
#define SB 1600          // scatter blocks (first in grid: latency overlaps gemm)
#define GB2 782          // gemm blocks: ceil(100000/128)
#define CSTRIDE 16       // cnt padded to 1 counter per 64B line (atomic decontention)

typedef unsigned short u16;
typedef unsigned int u32;
typedef __attribute__((ext_vector_type(8))) short bf16x8;
typedef __attribute__((ext_vector_type(8))) unsigned short ushort8;
typedef __attribute__((ext_vector_type(4))) float f32x4;

__device__ __forceinline__ float bf2f(u16 u){ return __uint_as_float(((u32)u) << 16); }
__device__ __forceinline__ u16 f2bf(float f){
  u32 x = __float_as_uint(f);
  return (u16)((x + 0x7fffu + ((x >> 16) & 1u)) >> 16);   // RNE
}

// ---------------------------------------------------------------------------
// k_prep: block 0 -> he_t;  blocks 1..128 -> Wt transpose+cast;  all -> zero cnt
// ---------------------------------------------------------------------------
__global__ void k_prep(const float* __restrict__ edge_emb, const float* __restrict__ Wr,
                       const float* __restrict__ a_e, const float* __restrict__ W,
                       const float* __restrict__ res_w,
                       float* __restrict__ he_t, u16* __restrict__ Wt,
                       int* __restrict__ cnt){
  const int b = blockIdx.x, tid = threadIdx.x;
  // zero padded cnt (NNODES*CSTRIDE ints = 6.4MB) with int4 stores
  int4 z4 = make_int4(0, 0, 0, 0);
  for (int i = b * 256 + tid; i < NNODES * CSTRIDE / 4; i += gridDim.x * 256)
    ((int4*)cnt)[i] = z4;

  if (b == 0){
    __shared__ float sc[NET * 128];
    for (int idx = tid; idx < NET * 128; idx += 256){
      int t = idx >> 7, o = idx & 127;
      float s = 0.f;
      #pragma unroll
      for (int e = 0; e < EDIM; ++e)
        s += edge_emb[t * EDIM + e] * Wr[t * EDIM * 128 + e * 128 + o];
      sc[idx] = s * a_e[o];
    }
    __syncthreads();
    if (tid < NET * HEADS){
      int t = tid >> 2, h = tid & 3;
      float s = 0.f;
      #pragma unroll
      for (int d = 0; d < EDIM; ++d) s += sc[t * 128 + h * EDIM + d];
      he_t[tid] = s;
    }
  } else {
    int idx = (b - 1) * 256 + tid;     // 128 blocks cover 256*128
    int n = idx >> 7, k = idx & 127;
    float v = (n < 128) ? W[k * 128 + n] : res_w[k * 128 + (n - 128)];
    Wt[idx] = f2bf(v);
  }
}

// ---------------------------------------------------------------------------
// k_main: blocks [0,SB): bucket scatter rtp[c*CAP+pos] = row | etype<<17
//         blocks [SB,SB+GB2): MFMA GEMM, 128 rows x 256 cols, Wt in LDS.
//   gemm cols 0-127 -> emb bf16 + h_l/h_r; cols 128-255 -> d_out fp32 residual.
// ---------------------------------------------------------------------------
__global__ __launch_bounds__(256) void k_main(
    const float* __restrict__ hmat, const u16* __restrict__ Wt,
    const float* __restrict__ res_b, const float* __restrict__ a_l,
    const float* __restrict__ a_r, u16* __restrict__ emb, float* __restrict__ outres,
    float* __restrict__ h_l, float* __restrict__ h_r,
    const int* __restrict__ row, const int* __restrict__ col,
    const int* __restrict__ et, int* __restrict__ cnt, int* __restrict__ rtp){
  __shared__ u16 Wl[128 * 136];        // 34.8 KB (2-way bank spread = free)
  const int tid = threadIdx.x;

  if (blockIdx.x < SB){                // ---- scatter part ----
    for (int e = blockIdx.x * 256 + tid; e < NEDGES; e += SB * 256){
      int c = col[e];
      int pos = atomicAdd(&cnt[c * CSTRIDE], 1);   // 1 counter per 64B line
      if (pos < CAP) rtp[c * CAP + pos] = row[e] | (et[e] << 17);
    }
    return;
  }

  // ---- GEMM part ----
  const int gb = blockIdx.x - SB;
  const int wid = tid >> 6, lane = tid & 63;
  const int m0 = gb * 128 + wid * 32;
  const int mcol = lane & 15, quad = lane >> 4;

  // A fragments: 2 row-tiles x 4 k-steps, fp32 -> bf16 in-register
  bf16x8 A[2][4];
  #pragma unroll
  for (int mt = 0; mt < 2; ++mt){
    int r = m0 + mt * 16 + mcol;
    int rc = r < NNODES ? r : NNODES - 1;
    const float* hrow = &hmat[rc * 128 + quad * 8];
    #pragma unroll
    for (int ks = 0; ks < 4; ++ks){
      float4 a0 = *(const float4*)&hrow[ks * 32];
      float4 a1 = *(const float4*)&hrow[ks * 32 + 4];
      A[mt][ks][0] = (short)f2bf(a0.x); A[mt][ks][1] = (short)f2bf(a0.y);
      A[mt][ks][2] = (short)f2bf(a0.z); A[mt][ks][3] = (short)f2bf(a0.w);
      A[mt][ks][4] = (short)f2bf(a1.x); A[mt][ks][5] = (short)f2bf(a1.y);
      A[mt][ks][6] = (short)f2bf(a1.z); A[mt][ks][7] = (short)f2bf(a1.w);
    }
  }

  float pl[2][4] = {}, pr[2][4] = {};
  #pragma unroll
  for (int phase = 0; phase < 2; ++phase){
    if (phase) __syncthreads();
    // stage 128 rows of Wt (32 KB) -> LDS, 8 x 16B per thread
    #pragma unroll
    for (int j = 0; j < 8; ++j){
      int cid = tid + j * 256;          // 2048 chunks of ushort8
      int rowL = cid >> 4, k8 = cid & 15;
      *(uint4*)&Wl[rowL * 136 + k8 * 8] =
          *(const uint4*)&Wt[(phase * 128 + rowL) * 128 + k8 * 8];
    }
    __syncthreads();

    #pragma unroll
    for (int ntl = 0; ntl < 8; ++ntl){
      bf16x8 B[4];
      const u16* bp = &Wl[(ntl * 16 + mcol) * 136 + quad * 8];
      #pragma unroll
      for (int ks = 0; ks < 4; ++ks) B[ks] = *(const bf16x8*)&bp[ks * 32];

      f32x4 acc[2] = {{0.f,0.f,0.f,0.f},{0.f,0.f,0.f,0.f}};
      #pragma unroll
      for (int ks = 0; ks < 4; ++ks){
        acc[0] = __builtin_amdgcn_mfma_f32_16x16x32_bf16(A[0][ks], B[ks], acc[0], 0, 0, 0);
        acc[1] = __builtin_amdgcn_mfma_f32_16x16x32_bf16(A[1][ks], B[ks], acc[1], 0, 0, 0);
      }

      const int c = ntl * 16 + mcol;      // column within the 128-col phase
      if (phase == 0){
        float alc = a_l[c], arc = a_r[c];
        #pragma unroll
        for (int mt = 0; mt < 2; ++mt){
          #pragma unroll
          for (int reg = 0; reg < 4; ++reg){
            int rw = m0 + mt * 16 + quad * 4 + reg;
            if (rw < NNODES) emb[rw * 128 + c] = f2bf(acc[mt][reg]);
            pl[mt][reg] += alc * acc[mt][reg];
            pr[mt][reg] += arc * acc[mt][reg];
          }
        }
        if (ntl & 1){            // head h = ntl>>1 complete
          int h = ntl >> 1;
          #pragma unroll
          for (int mt = 0; mt < 2; ++mt){
            #pragma unroll
            for (int reg = 0; reg < 4; ++reg){
              float s0 = pl[mt][reg], s1 = pr[mt][reg];
              #pragma unroll
              for (int off = 1; off < 16; off <<= 1){
                s0 += __shfl_xor(s0, off, 64);
                s1 += __shfl_xor(s1, off, 64);
              }
              int rw = m0 + mt * 16 + quad * 4 + reg;
              if (mcol == 0 && rw < NNODES){
                h_l[rw * 4 + h] = s0;
                h_r[rw * 4 + h] = s1;
              }
              pl[mt][reg] = 0.f; pr[mt][reg] = 0.f;
            }
          }
        }
      } else {
        float rb = res_b[c];
        #pragma unroll
        for (int mt = 0; mt < 2; ++mt){
          #pragma unroll
          for (int reg = 0; reg < 4; ++reg){
            int rw = m0 + mt * 16 + quad * 4 + reg;
            if (rw < NNODES) outres[rw * 128 + c] = acc[mt][reg] + rb;
          }
        }
      }
    }
  }
}

// ---------------------------------------------------------------------------
// k_nodeagg: one wave per node.
// Prologue (lane = slot, parallel): w[4] = exp(leaky(h_l[r]+h_r[n]+he[t]))
//   -> LDS (fp32), r -> LDS.  he table read straight from global (L1-resident).
// Main loop: QUARTER-wave per edge (16 lanes x ushort8 = 256B row), 4 edges
//   per step, 2 steps unrolled -> 8 edges / iter, 2 independent dwordx4
//   gathers in flight per wave (MLP), 4x fewer iterations than half-wave.
// Fused normalize + permute + fp32 residual (preloaded in out) + ELU.
// ---------------------------------------------------------------------------
__global__ __launch_bounds__(256) void k_nodeagg(const int* __restrict__ cnt,
    const int* __restrict__ rtp, const float* __restrict__ h_l,
    const float* __restrict__ h_r, const float* __restrict__ he_t_g,
    const u16* __restrict__ emb, float* __restrict__ out){
  __shared__ float wl[4][CAP][4];      // [wave][slot][head], fp32
  __shared__ int   rl[4][CAP];

  const int wid = threadIdx.x >> 6;
  const int n = blockIdx.x * 4 + wid;            // grid*4 == NNODES exactly
  const int lane = threadIdx.x & 63;
  int deg = cnt[n * CSTRIDE]; if (deg > CAP) deg = CAP;
  const int base = n * CAP;

  // ---- prologue: per-slot weights, all slots in parallel ----
  {
    bool v = lane < deg;
    int rt = rtp[base + (v ? lane : 0)];
    int r = rt & 0x1FFFF, t = (rt >> 17) & 7;
    float4 hl = *(const float4*)&h_l[r * 4];
    float4 hr = *(const float4*)&h_r[n * 4];
    float4 he = *(const float4*)&he_t_g[t * 4];
    float x0 = hl.x + hr.x + he.x; x0 = x0 > 0.f ? x0 : NEG * x0;
    float x1 = hl.y + hr.y + he.y; x1 = x1 > 0.f ? x1 : NEG * x1;
    float x2 = hl.z + hr.z + he.z; x2 = x2 > 0.f ? x2 : NEG * x2;
    float x3 = hl.w + hr.w + he.w; x3 = x3 > 0.f ? x3 : NEG * x3;
    float4 w4 = make_float4(__expf(x0), __expf(x1), __expf(x2), __expf(x3));
    *(float4*)&wl[wid][lane][0] = w4;
    rl[wid][lane] = r;
  }
  __syncthreads();

  const int q = lane >> 4;             // quarter 0..3 -> edge i+q
  const int L = lane & 15;             // dims L*8 .. L*8+7 (emb layout [head][32])
  const int h = L >> 2;                // head of this lane's 8 dims

  float acc[8] = {0.f,0.f,0.f,0.f,0.f,0.f,0.f,0.f};
  float ds = 0.f;
  for (int i = 0; i < deg; i += 8){
    int i0 = i + q, i1 = i + 4 + q;
    bool v0 = i0 < deg, v1 = i1 < deg;
    int ii0 = v0 ? i0 : 0, ii1 = v1 ? i1 : 0;
    int r0 = rl[wid][ii0];                       // LDS broadcast
    int r1 = rl[wid][ii1];
    float w0 = v0 ? wl[wid][ii0][h] : 0.f;       // LDS broadcast
    float w1 = v1 ? wl[wid][ii1][h] : 0.f;
    ushort8 u0 = *(const ushort8*)&emb[r0 * 128 + L * 8];
    ushort8 u1 = *(const ushort8*)&emb[r1 * 128 + L * 8];
    #pragma unroll
    for (int k = 0; k < 8; ++k) acc[k] += w0 * bf2f((u16)u0[k]);
    ds += w0;
    #pragma unroll
    for (int k = 0; k < 8; ++k) acc[k] += w1 * bf2f((u16)u1[k]);
    ds += w1;
  }

  // combine the 4 quarters: lanes L, L+16, L+32, L+48 hold partials of same dims
  #pragma unroll
  for (int k = 0; k < 8; ++k){
    acc[k] += __shfl_xor(acc[k], 16, 64);
    acc[k] += __shfl_xor(acc[k], 32, 64);
  }
  ds += __shfl_xor(ds, 16, 64);
  ds += __shfl_xor(ds, 32, 64);

  if (q == 0){
    float inv = (deg > 0) ? 1.f / ds : 0.f;
    // dim j = L*8+k -> out offset n*128 + (j&31)*4 + head
    //              = n*128 + (L&3)*32 + k*4 + (L>>2)
    int ob = n * 128 + (L & 3) * 32 + (L >> 2);
    #pragma unroll
    for (int k = 0; k < 8; ++k){
      int o = ob + k * 4;
      float v = acc[k] * inv + out[o];
      out[o] = v > 0.f ? v : (__expf(v) - 1.f);
    }
  }
}

// ---------------------------------------------------------------------------
extern "C" void kernel_launch(void* const* d_in, const int* in_sizes, int n_in,
                              void* d_out, int out_size, void* d_ws, size_t ws_size,
                              hipStream_t stream){
  const float* hmat     = (const float*)d_in[0];
  const int*   row      = (const int*)d_in[1];
  const int*   col      = (const int*)d_in[2];
  const int*   et       = (const int*)d_in[3];
  const float* edge_emb = (const float*)d_in[4];
  const float* W        = (const float*)d_in[5];
  const float* Wr       = (const float*)d_in[6];
  const float* a_l      = (const float*)d_in[7];
  const float* a_r      = (const float*)d_in[8];
  const float* a_e      = (const float*)d_in[9];
  const float* res_w    = (const float*)d_in[10];
  const float* res_b    = (const float*)d_in[11];
  float* out = (float*)d_out;

  char* ws = (char*)d_ws;
  // he_t 256 | Wt 64K | h_l 1.6M | h_r 1.6M | cnt 6.4M (padded) | rtp 25.6M |
  // emb(bf16) 25.6M    (~61 MB)
  float* he_t   = (float*)(ws);
  u16*   Wt     = (u16*)  (ws + 256);
  float* h_l    = (float*)(ws + 65792);
  float* h_r    = (float*)(ws + 1665792);
  int*   cnt    = (int*)  (ws + 3265792);
  int*   rtp    = (int*)  (ws + 9665792);
  u16*   emb    = (u16*)  (ws + 35265792);

  hipLaunchKernelGGL(k_prep, dim3(129), dim3(256), 0, stream,
                     edge_emb, Wr, a_e, W, res_w, he_t, Wt, cnt);
  hipLaunchKernelGGL(k_main, dim3(SB + GB2), dim3(256), 0, stream,
                     hmat, Wt, res_b, a_l, a_r, emb, out, h_l, h_r,
                     row, col, et, cnt, rtp);
  hipLaunchKernelGGL(k_nodeagg, dim3(NNODES / 4), dim3(256), 0, stream,
                     cnt, rtp, h_l, h_r, he_t, emb, out);
}

// Round 7
// 360.589 us; speedup vs baseline: 1.0675x; 1.0108x over previous
//
#include <hip/hip_runtime.h>

#define NNODES 100000
#define NEDGES 1600000
#define INDIM 128
#define OUTD 32
#define HEADS 4
#define EDIM 32
#define NET 8
#define NEG 0.2f
#define CAP 64           // per-node bucket capacity (Poisson(16): P(>64) ~ 1e-20)
#define SB2 782          // scatter blocks: 8 edges/thread, NEDGES/8=200000 threads
#define GB2 782          // gemm blocks: ceil(100000/128)
#define CSTRIDE 16       // cnt padded to 1 counter per 64B line

typedef unsigned short u16;
typedef unsigned int u32;
typedef __attribute__((ext_vector_type(8))) short bf16x8;
typedef __attribute__((ext_vector_type(8))) unsigned short ushort8;
typedef __attribute__((ext_vector_type(4))) float f32x4;

__device__ __forceinline__ float bf2f(u16 u){ return __uint_as_float(((u32)u) << 16); }
__device__ __forceinline__ u16 f2bf(float f){
  u32 x = __float_as_uint(f);
  return (u16)((x + 0x7fffu + ((x >> 16) & 1u)) >> 16);   // RNE
}

// ---------------------------------------------------------------------------
// k_prep: block 0 -> he_t;  blocks 1..128 -> Wt transpose+cast;  all -> zero cnt
// ---------------------------------------------------------------------------
__global__ void k_prep(const float* __restrict__ edge_emb, const float* __restrict__ Wr,
                       const float* __restrict__ a_e, const float* __restrict__ W,
                       const float* __restrict__ res_w,
                       float* __restrict__ he_t, u16* __restrict__ Wt,
                       int* __restrict__ cnt){
  const int b = blockIdx.x, tid = threadIdx.x;
  // zero padded cnt (NNODES*CSTRIDE ints = 6.4MB) with int4 stores
  int4 z4 = make_int4(0, 0, 0, 0);
  for (int i = b * 256 + tid; i < NNODES * CSTRIDE / 4; i += gridDim.x * 256)
    ((int4*)cnt)[i] = z4;

  if (b == 0){
    __shared__ float sc[NET * 128];
    for (int idx = tid; idx < NET * 128; idx += 256){
      int t = idx >> 7, o = idx & 127;
      float s = 0.f;
      #pragma unroll
      for (int e = 0; e < EDIM; ++e)
        s += edge_emb[t * EDIM + e] * Wr[t * EDIM * 128 + e * 128 + o];
      sc[idx] = s * a_e[o];
    }
    __syncthreads();
    if (tid < NET * HEADS){
      int t = tid >> 2, h = tid & 3;
      float s = 0.f;
      #pragma unroll
      for (int d = 0; d < EDIM; ++d) s += sc[t * 128 + h * EDIM + d];
      he_t[tid] = s;
    }
  } else {
    int idx = (b - 1) * 256 + tid;     // 128 blocks cover 256*128
    int n = idx >> 7, k = idx & 127;
    float v = (n < 128) ? W[k * 128 + n] : res_w[k * 128 + (n - 128)];
    Wt[idx] = f2bf(v);
  }
}

// ---------------------------------------------------------------------------
// k_main: blocks [0,SB2): scatter, 8 consecutive edges/thread, 8 atomics
//   in flight (MLP) -> rtp[c*CAP+pos] = row | etype<<17.
// blocks [SB2,SB2+GB2): MFMA GEMM, 128 rows x 256 cols, B read from L2
//   (NO LDS -> scatter occupancy not LDS-capped, no barriers).
//   gemm cols 0-127 -> emb bf16 + h_l/h_r; cols 128-255 -> d_out fp32 residual.
// ---------------------------------------------------------------------------
__global__ __launch_bounds__(256) void k_main(
    const float* __restrict__ hmat, const u16* __restrict__ Wt,
    const float* __restrict__ res_b, const float* __restrict__ a_l,
    const float* __restrict__ a_r, u16* __restrict__ emb, float* __restrict__ outres,
    float* __restrict__ h_l, float* __restrict__ h_r,
    const int* __restrict__ row, const int* __restrict__ col,
    const int* __restrict__ et, int* __restrict__ cnt, int* __restrict__ rtp){
  const int tid = threadIdx.x;

  if (blockIdx.x < SB2){               // ---- scatter part ----
    int s = blockIdx.x * 256 + tid;
    if (s < NEDGES / 8){
      const int e0 = s * 8;
      int4 c0 = *(const int4*)&col[e0];
      int4 c1 = *(const int4*)&col[e0 + 4];
      int4 r0 = *(const int4*)&row[e0];
      int4 r1 = *(const int4*)&row[e0 + 4];
      int4 t0 = *(const int4*)&et[e0];
      int4 t1 = *(const int4*)&et[e0 + 4];
      int p0 = atomicAdd(&cnt[c0.x * CSTRIDE], 1);
      int p1 = atomicAdd(&cnt[c0.y * CSTRIDE], 1);
      int p2 = atomicAdd(&cnt[c0.z * CSTRIDE], 1);
      int p3 = atomicAdd(&cnt[c0.w * CSTRIDE], 1);
      int p4 = atomicAdd(&cnt[c1.x * CSTRIDE], 1);
      int p5 = atomicAdd(&cnt[c1.y * CSTRIDE], 1);
      int p6 = atomicAdd(&cnt[c1.z * CSTRIDE], 1);
      int p7 = atomicAdd(&cnt[c1.w * CSTRIDE], 1);
      if (p0 < CAP) rtp[c0.x * CAP + p0] = r0.x | (t0.x << 17);
      if (p1 < CAP) rtp[c0.y * CAP + p1] = r0.y | (t0.y << 17);
      if (p2 < CAP) rtp[c0.z * CAP + p2] = r0.z | (t0.z << 17);
      if (p3 < CAP) rtp[c0.w * CAP + p3] = r0.w | (t0.w << 17);
      if (p4 < CAP) rtp[c1.x * CAP + p4] = r1.x | (t1.x << 17);
      if (p5 < CAP) rtp[c1.y * CAP + p5] = r1.y | (t1.y << 17);
      if (p6 < CAP) rtp[c1.z * CAP + p6] = r1.z | (t1.z << 17);
      if (p7 < CAP) rtp[c1.w * CAP + p7] = r1.w | (t1.w << 17);
    }
    return;
  }

  // ---- GEMM part (no LDS: B fragments straight from L2-resident Wt) ----
  const int gb = blockIdx.x - SB2;
  const int wid = tid >> 6, lane = tid & 63;
  const int m0 = gb * 128 + wid * 32;
  const int mcol = lane & 15, quad = lane >> 4;

  // A fragments: 2 row-tiles x 4 k-steps, fp32 -> bf16 in-register
  bf16x8 A[2][4];
  #pragma unroll
  for (int mt = 0; mt < 2; ++mt){
    int r = m0 + mt * 16 + mcol;
    int rc = r < NNODES ? r : NNODES - 1;
    const float* hrow = &hmat[rc * 128 + quad * 8];
    #pragma unroll
    for (int ks = 0; ks < 4; ++ks){
      float4 a0 = *(const float4*)&hrow[ks * 32];
      float4 a1 = *(const float4*)&hrow[ks * 32 + 4];
      A[mt][ks][0] = (short)f2bf(a0.x); A[mt][ks][1] = (short)f2bf(a0.y);
      A[mt][ks][2] = (short)f2bf(a0.z); A[mt][ks][3] = (short)f2bf(a0.w);
      A[mt][ks][4] = (short)f2bf(a1.x); A[mt][ks][5] = (short)f2bf(a1.y);
      A[mt][ks][6] = (short)f2bf(a1.z); A[mt][ks][7] = (short)f2bf(a1.w);
    }
  }

  float pl[2][4] = {}, pr[2][4] = {};
  #pragma unroll
  for (int phase = 0; phase < 2; ++phase){
    #pragma unroll
    for (int ntl = 0; ntl < 8; ++ntl){
      bf16x8 B[4];
      const u16* bp = &Wt[(phase * 128 + ntl * 16 + mcol) * 128 + quad * 8];
      #pragma unroll
      for (int ks = 0; ks < 4; ++ks) B[ks] = *(const bf16x8*)&bp[ks * 32];

      f32x4 acc[2] = {{0.f,0.f,0.f,0.f},{0.f,0.f,0.f,0.f}};
      #pragma unroll
      for (int ks = 0; ks < 4; ++ks){
        acc[0] = __builtin_amdgcn_mfma_f32_16x16x32_bf16(A[0][ks], B[ks], acc[0], 0, 0, 0);
        acc[1] = __builtin_amdgcn_mfma_f32_16x16x32_bf16(A[1][ks], B[ks], acc[1], 0, 0, 0);
      }

      const int c = ntl * 16 + mcol;      // column within the 128-col phase
      if (phase == 0){
        float alc = a_l[c], arc = a_r[c];
        #pragma unroll
        for (int mt = 0; mt < 2; ++mt){
          #pragma unroll
          for (int reg = 0; reg < 4; ++reg){
            int rw = m0 + mt * 16 + quad * 4 + reg;
            if (rw < NNODES) emb[rw * 128 + c] = f2bf(acc[mt][reg]);
            pl[mt][reg] += alc * acc[mt][reg];
            pr[mt][reg] += arc * acc[mt][reg];
          }
        }
        if (ntl & 1){            // head h = ntl>>1 complete
          int h = ntl >> 1;
          #pragma unroll
          for (int mt = 0; mt < 2; ++mt){
            #pragma unroll
            for (int reg = 0; reg < 4; ++reg){
              float s0 = pl[mt][reg], s1 = pr[mt][reg];
              #pragma unroll
              for (int off = 1; off < 16; off <<= 1){
                s0 += __shfl_xor(s0, off, 64);
                s1 += __shfl_xor(s1, off, 64);
              }
              int rw = m0 + mt * 16 + quad * 4 + reg;
              if (mcol == 0 && rw < NNODES){
                h_l[rw * 4 + h] = s0;
                h_r[rw * 4 + h] = s1;
              }
              pl[mt][reg] = 0.f; pr[mt][reg] = 0.f;
            }
          }
        }
      } else {
        float rb = res_b[c];
        #pragma unroll
        for (int mt = 0; mt < 2; ++mt){
          #pragma unroll
          for (int reg = 0; reg < 4; ++reg){
            int rw = m0 + mt * 16 + quad * 4 + reg;
            if (rw < NNODES) outres[rw * 128 + c] = acc[mt][reg] + rb;
          }
        }
      }
    }
  }
}

// ---------------------------------------------------------------------------
// k_nodeagg: one wave per node.
// Prologue (lane = slot, parallel): w[4] = exp(leaky(h_l[r]+h_r[n]+he[t]))
//   -> LDS (fp32), r -> LDS.  he table read straight from global (L1-resident).
// Main loop: QUARTER-wave per edge (16 lanes x ushort8 = 256B row), 4 edges
//   per step, 2 steps unrolled -> 8 edges / iter, 2 independent dwordx4
//   gathers in flight per wave (MLP), 4x fewer iterations than half-wave.
// Fused normalize + permute + fp32 residual (preloaded in out) + ELU.
// ---------------------------------------------------------------------------
__global__ __launch_bounds__(256) void k_nodeagg(const int* __restrict__ cnt,
    const int* __restrict__ rtp, const float* __restrict__ h_l,
    const float* __restrict__ h_r, const float* __restrict__ he_t_g,
    const u16* __restrict__ emb, float* __restrict__ out){
  __shared__ float wl[4][CAP][4];      // [wave][slot][head], fp32
  __shared__ int   rl[4][CAP];

  const int wid = threadIdx.x >> 6;
  const int n = blockIdx.x * 4 + wid;            // grid*4 == NNODES exactly
  const int lane = threadIdx.x & 63;
  int deg = cnt[n * CSTRIDE]; if (deg > CAP) deg = CAP;
  const int base = n * CAP;

  // ---- prologue: per-slot weights, all slots in parallel ----
  {
    bool v = lane < deg;
    int rt = rtp[base + (v ? lane : 0)];
    int r = rt & 0x1FFFF, t = (rt >> 17) & 7;
    float4 hl = *(const float4*)&h_l[r * 4];
    float4 hr = *(const float4*)&h_r[n * 4];
    float4 he = *(const float4*)&he_t_g[t * 4];
    float x0 = hl.x + hr.x + he.x; x0 = x0 > 0.f ? x0 : NEG * x0;
    float x1 = hl.y + hr.y + he.y; x1 = x1 > 0.f ? x1 : NEG * x1;
    float x2 = hl.z + hr.z + he.z; x2 = x2 > 0.f ? x2 : NEG * x2;
    float x3 = hl.w + hr.w + he.w; x3 = x3 > 0.f ? x3 : NEG * x3;
    float4 w4 = make_float4(__expf(x0), __expf(x1), __expf(x2), __expf(x3));
    *(float4*)&wl[wid][lane][0] = w4;
    rl[wid][lane] = r;
  }
  __syncthreads();

  const int q = lane >> 4;             // quarter 0..3 -> edge i+q
  const int L = lane & 15;             // dims L*8 .. L*8+7 (emb layout [head][32])
  const int h = L >> 2;                // head of this lane's 8 dims

  float acc[8] = {0.f,0.f,0.f,0.f,0.f,0.f,0.f,0.f};
  float ds = 0.f;
  for (int i = 0; i < deg; i += 8){
    int i0 = i + q, i1 = i + 4 + q;
    bool v0 = i0 < deg, v1 = i1 < deg;
    int ii0 = v0 ? i0 : 0, ii1 = v1 ? i1 : 0;
    int r0 = rl[wid][ii0];                       // LDS broadcast
    int r1 = rl[wid][ii1];
    float w0 = v0 ? wl[wid][ii0][h] : 0.f;       // LDS broadcast
    float w1 = v1 ? wl[wid][ii1][h] : 0.f;
    ushort8 u0 = *(const ushort8*)&emb[r0 * 128 + L * 8];
    ushort8 u1 = *(const ushort8*)&emb[r1 * 128 + L * 8];
    #pragma unroll
    for (int k = 0; k < 8; ++k) acc[k] += w0 * bf2f((u16)u0[k]);
    ds += w0;
    #pragma unroll
    for (int k = 0; k < 8; ++k) acc[k] += w1 * bf2f((u16)u1[k]);
    ds += w1;
  }

  // combine the 4 quarters: lanes L, L+16, L+32, L+48 hold partials of same dims
  #pragma unroll
  for (int k = 0; k < 8; ++k){
    acc[k] += __shfl_xor(acc[k], 16, 64);
    acc[k] += __shfl_xor(acc[k], 32, 64);
  }
  ds += __shfl_xor(ds, 16, 64);
  ds += __shfl_xor(ds, 32, 64);

  if (q == 0){
    float inv = (deg > 0) ? 1.f / ds : 0.f;
    // dim j = L*8+k -> out offset n*128 + (j&31)*4 + head
    //              = n*128 + (L&3)*32 + k*4 + (L>>2)
    int ob = n * 128 + (L & 3) * 32 + (L >> 2);
    #pragma unroll
    for (int k = 0; k < 8; ++k){
      int o = ob + k * 4;
      float v = acc[k] * inv + out[o];
      out[o] = v > 0.f ? v : (__expf(v) - 1.f);
    }
  }
}

// ---------------------------------------------------------------------------
extern "C" void kernel_launch(void* const* d_in, const int* in_sizes, int n_in,
                              void* d_out, int out_size, void* d_ws, size_t ws_size,
                              hipStream_t stream){
  const float* hmat     = (const float*)d_in[0];
  const int*   row      = (const int*)d_in[1];
  const int*   col      = (const int*)d_in[2];
  const int*   et       = (const int*)d_in[3];
  const float* edge_emb = (const float*)d_in[4];
  const float* W        = (const float*)d_in[5];
  const float* Wr       = (const float*)d_in[6];
  const float* a_l      = (const float*)d_in[7];
  const float* a_r      = (const float*)d_in[8];
  const float* a_e      = (const float*)d_in[9];
  const float* res_w    = (const float*)d_in[10];
  const float* res_b    = (const float*)d_in[11];
  float* out = (float*)d_out;

  char* ws = (char*)d_ws;
  // he_t 256 | Wt 64K | h_l 1.6M | h_r 1.6M | cnt 6.4M (padded) | rtp 25.6M |
  // emb(bf16) 25.6M    (~61 MB)
  float* he_t   = (float*)(ws);
  u16*   Wt     = (u16*)  (ws + 256);
  float* h_l    = (float*)(ws + 65792);
  float* h_r    = (float*)(ws + 1665792);
  int*   cnt    = (int*)  (ws + 3265792);
  int*   rtp    = (int*)  (ws + 9665792);
  u16*   emb    = (u16*)  (ws + 35265792);

  hipLaunchKernelGGL(k_prep, dim3(129), dim3(256), 0, stream,
                     edge_emb, Wr, a_e, W, res_w, he_t, Wt, cnt);
  hipLaunchKernelGGL(k_main, dim3(SB2 + GB2), dim3(256), 0, stream,
                     hmat, Wt, res_b, a_l, a_r, emb, out, h_l, h_r,
                     row, col, et, cnt, rtp);
  hipLaunchKernelGGL(k_nodeagg, dim3(NNODES / 4), dim3(256), 0, stream,
                     cnt, rtp, h_l, h_r, he_t, emb, out);
}

// Round 9
// 305.536 us; speedup vs baseline: 1.2599x; 1.1802x over previous
//
#include <hip/hip_runtime.h>

#define NNODES 100000
#define NEDGES 1600000
#define INDIM 128
#define OUTD 32
#define HEADS 4
#define EDIM 32
#define NET 8
#define NEG 0.2f
#define CAP 64           // per-node bucket capacity (Poisson(16): P(>64) ~ 1e-20)
#define RB 392           // coarse buckets: node >> 8, 392*256 = 100352 >= NNODES
#define SEGCAP 4608      // per-bucket segment cap (mean 4081, +8.2 sigma)
#define PBLK 196         // partition blocks, 8192 edges each (196*8192 >= NEDGES)
#define EPB 8192
#define GB2 782          // gemm blocks: ceil(100000/128)

typedef unsigned short u16;
typedef unsigned int u32;
typedef __attribute__((ext_vector_type(8))) short bf16x8;
typedef __attribute__((ext_vector_type(8))) unsigned short ushort8;
typedef __attribute__((ext_vector_type(4))) float f32x4;

__device__ __forceinline__ float bf2f(u16 u){ return __uint_as_float(((u32)u) << 16); }
__device__ __forceinline__ u16 f2bf(float f){
  u32 x = __float_as_uint(f);
  return (u16)((x + 0x7fffu + ((x >> 16) & 1u)) >> 16);   // RNE
}

// ---------------------------------------------------------------------------
// k_prep: zero cnt + gcnt; block 0 -> he_t; blocks 1..128 -> Wt transpose+cast
// ---------------------------------------------------------------------------
__global__ void k_prep(const float* __restrict__ edge_emb, const float* __restrict__ Wr,
                       const float* __restrict__ a_e, const float* __restrict__ W,
                       const float* __restrict__ res_w,
                       float* __restrict__ he_t, u16* __restrict__ Wt,
                       int* __restrict__ cnt, int* __restrict__ gcnt){
  const int b = blockIdx.x, tid = threadIdx.x;
  int4 z4 = make_int4(0, 0, 0, 0);
  for (int i = b * 256 + tid; i < NNODES / 4; i += gridDim.x * 256)
    ((int4*)cnt)[i] = z4;

  if (b == 0){
    for (int t = tid; t < RB; t += 256) gcnt[t] = 0;
    __shared__ float sc[NET * 128];
    for (int idx = tid; idx < NET * 128; idx += 256){
      int t = idx >> 7, o = idx & 127;
      float s = 0.f;
      #pragma unroll
      for (int e = 0; e < EDIM; ++e)
        s += edge_emb[t * EDIM + e] * Wr[t * EDIM * 128 + e * 128 + o];
      sc[idx] = s * a_e[o];
    }
    __syncthreads();
    if (tid < NET * HEADS){
      int t = tid >> 2, h = tid & 3;
      float s = 0.f;
      #pragma unroll
      for (int d = 0; d < EDIM; ++d) s += sc[t * 128 + h * EDIM + d];
      he_t[tid] = s;
    }
  } else {
    int idx = (b - 1) * 256 + tid;     // 128 blocks cover 256*128
    int n = idx >> 7, k = idx & 127;
    float v = (n < 128) ? W[k * 128 + n] : res_w[k * 128 + (n - 128)];
    Wt[idx] = f2bf(v);
  }
}

// ---------------------------------------------------------------------------
// k_fusedA: blocks [0,PBLK): edge partition into RB coarse buckets.
//   Phase 1: LDS histogram + per-edge local rank (LDS atomics, CU-local).
//   Phase 2: ONE global atomic per (block,bucket) reserves segment space
//            (77K global atomics total vs 1.6M before -> under the ~8/ns
//             device-atomic service ceiling measured in r2-r7).
//   Phase 3: write packed edge (row|et<<17|c_low<<20) into bucket segment.
// blocks [PBLK,PBLK+GB2): MFMA GEMM (unchanged from round 7, measured).
// ---------------------------------------------------------------------------
__global__ __launch_bounds__(256) void k_fusedA(
    const float* __restrict__ hmat, const u16* __restrict__ Wt,
    const float* __restrict__ res_b, const float* __restrict__ a_l,
    const float* __restrict__ a_r, u16* __restrict__ emb, float* __restrict__ outres,
    float* __restrict__ h_l, float* __restrict__ h_r,
    const int* __restrict__ row, const int* __restrict__ col,
    const int* __restrict__ et, int* __restrict__ gcnt, u32* __restrict__ seg){
  __shared__ u16 rankL[EPB];           // 16 KB
  __shared__ int lcnt[RB];             // 1.57 KB
  __shared__ int gbaseL[RB];           // 1.57 KB
  const int tid = threadIdx.x;

  if (blockIdx.x < PBLK){              // ---- partition part ----
    for (int t = tid; t < RB; t += 256) lcnt[t] = 0;
    __syncthreads();
    const int base = blockIdx.x * EPB;
    // phase 1: strided coalesced int4 loads, LDS hist + local ranks
    #pragma unroll
    for (int j = 0; j < 8; ++j){
      int e0 = base + j * 1024 + tid * 4;
      if (e0 < NEDGES){
        int4 c4 = *(const int4*)&col[e0];
        int lp = j * 1024 + tid * 4;
        rankL[lp + 0] = (u16)atomicAdd(&lcnt[c4.x >> 8], 1);
        rankL[lp + 1] = (u16)atomicAdd(&lcnt[c4.y >> 8], 1);
        rankL[lp + 2] = (u16)atomicAdd(&lcnt[c4.z >> 8], 1);
        rankL[lp + 3] = (u16)atomicAdd(&lcnt[c4.w >> 8], 1);
      }
    }
    __syncthreads();
    // phase 2: reserve global segment space, one atomic per non-empty bucket
    for (int t = tid; t < RB; t += 256){
      int c = lcnt[t];
      gbaseL[t] = (c > 0) ? atomicAdd(&gcnt[t], c) : 0;
    }
    __syncthreads();
    // phase 3: write packed edges into segments (contiguous runs per bucket)
    #pragma unroll
    for (int j = 0; j < 8; ++j){
      int e0 = base + j * 1024 + tid * 4;
      if (e0 < NEDGES){
        int4 c4 = *(const int4*)&col[e0];
        int4 r4 = *(const int4*)&row[e0];
        int4 t4 = *(const int4*)&et[e0];
        int lp = j * 1024 + tid * 4;
        int b0 = c4.x >> 8, i0 = gbaseL[b0] + rankL[lp + 0];
        if (i0 < SEGCAP) seg[b0 * SEGCAP + i0] =
            (u32)r4.x | ((u32)t4.x << 17) | ((u32)(c4.x & 255) << 20);
        int b1 = c4.y >> 8, i1 = gbaseL[b1] + rankL[lp + 1];
        if (i1 < SEGCAP) seg[b1 * SEGCAP + i1] =
            (u32)r4.y | ((u32)t4.y << 17) | ((u32)(c4.y & 255) << 20);
        int b2 = c4.z >> 8, i2 = gbaseL[b2] + rankL[lp + 2];
        if (i2 < SEGCAP) seg[b2 * SEGCAP + i2] =
            (u32)r4.z | ((u32)t4.z << 17) | ((u32)(c4.z & 255) << 20);
        int b3 = c4.w >> 8, i3 = gbaseL[b3] + rankL[lp + 3];
        if (i3 < SEGCAP) seg[b3 * SEGCAP + i3] =
            (u32)r4.w | ((u32)t4.w << 17) | ((u32)(c4.w & 255) << 20);
      }
    }
    return;
  }

  // ---- GEMM part (no LDS use; B fragments straight from L2-resident Wt) ----
  const int gb = blockIdx.x - PBLK;
  const int wid = tid >> 6, lane = tid & 63;
  const int m0 = gb * 128 + wid * 32;
  const int mcol = lane & 15, quad = lane >> 4;

  bf16x8 A[2][4];
  #pragma unroll
  for (int mt = 0; mt < 2; ++mt){
    int r = m0 + mt * 16 + mcol;
    int rc = r < NNODES ? r : NNODES - 1;
    const float* hrow = &hmat[rc * 128 + quad * 8];
    #pragma unroll
    for (int ks = 0; ks < 4; ++ks){
      float4 a0 = *(const float4*)&hrow[ks * 32];
      float4 a1 = *(const float4*)&hrow[ks * 32 + 4];
      A[mt][ks][0] = (short)f2bf(a0.x); A[mt][ks][1] = (short)f2bf(a0.y);
      A[mt][ks][2] = (short)f2bf(a0.z); A[mt][ks][3] = (short)f2bf(a0.w);
      A[mt][ks][4] = (short)f2bf(a1.x); A[mt][ks][5] = (short)f2bf(a1.y);
      A[mt][ks][6] = (short)f2bf(a1.z); A[mt][ks][7] = (short)f2bf(a1.w);
    }
  }

  float pl[2][4] = {}, pr[2][4] = {};
  #pragma unroll
  for (int phase = 0; phase < 2; ++phase){
    #pragma unroll
    for (int ntl = 0; ntl < 8; ++ntl){
      bf16x8 B[4];
      const u16* bp = &Wt[(phase * 128 + ntl * 16 + mcol) * 128 + quad * 8];
      #pragma unroll
      for (int ks = 0; ks < 4; ++ks) B[ks] = *(const bf16x8*)&bp[ks * 32];

      f32x4 acc[2] = {{0.f,0.f,0.f,0.f},{0.f,0.f,0.f,0.f}};
      #pragma unroll
      for (int ks = 0; ks < 4; ++ks){
        acc[0] = __builtin_amdgcn_mfma_f32_16x16x32_bf16(A[0][ks], B[ks], acc[0], 0, 0, 0);
        acc[1] = __builtin_amdgcn_mfma_f32_16x16x32_bf16(A[1][ks], B[ks], acc[1], 0, 0, 0);
      }

      const int c = ntl * 16 + mcol;      // column within the 128-col phase
      if (phase == 0){
        float alc = a_l[c], arc = a_r[c];
        #pragma unroll
        for (int mt = 0; mt < 2; ++mt){
          #pragma unroll
          for (int reg = 0; reg < 4; ++reg){
            int rw = m0 + mt * 16 + quad * 4 + reg;
            if (rw < NNODES) emb[rw * 128 + c] = f2bf(acc[mt][reg]);
            pl[mt][reg] += alc * acc[mt][reg];
            pr[mt][reg] += arc * acc[mt][reg];
          }
        }
        if (ntl & 1){            // head h = ntl>>1 complete
          int h = ntl >> 1;
          #pragma unroll
          for (int mt = 0; mt < 2; ++mt){
            #pragma unroll
            for (int reg = 0; reg < 4; ++reg){
              float s0 = pl[mt][reg], s1 = pr[mt][reg];
              #pragma unroll
              for (int off = 1; off < 16; off <<= 1){
                s0 += __shfl_xor(s0, off, 64);
                s1 += __shfl_xor(s1, off, 64);
              }
              int rw = m0 + mt * 16 + quad * 4 + reg;
              if (mcol == 0 && rw < NNODES){
                h_l[rw * 4 + h] = s0;
                h_r[rw * 4 + h] = s1;
              }
              pl[mt][reg] = 0.f; pr[mt][reg] = 0.f;
            }
          }
        }
      } else {
        float rb = res_b[c];
        #pragma unroll
        for (int mt = 0; mt < 2; ++mt){
          #pragma unroll
          for (int reg = 0; reg < 4; ++reg){
            int rw = m0 + mt * 16 + quad * 4 + reg;
            if (rw < NNODES) outres[rw * 128 + c] = acc[mt][reg] + rb;
          }
        }
      }
    }
  }
}

// ---------------------------------------------------------------------------
// k_bucket: one block per coarse bucket (256 nodes). Replays the bucket's
// segment through 256 LDS counters -> exact rtp positions + cnt. All rtp
// writes land in a 64-KB window per block (L2-friendly full-line writebacks).
// ---------------------------------------------------------------------------
__global__ __launch_bounds__(256) void k_bucket(const int* __restrict__ gcnt,
    const u32* __restrict__ seg, int* __restrict__ cnt, int* __restrict__ rtp){
  __shared__ int lc[256];
  const int b = blockIdx.x;
  const int tid = threadIdx.x;
  lc[tid] = 0;
  __syncthreads();
  int m = gcnt[b]; if (m > SEGCAP) m = SEGCAP;
  const u32* s = &seg[b * SEGCAP];
  const int nbase = b << 8;
  for (int i = tid; i < m; i += 256){
    u32 e = s[i];
    int cl = e >> 20;
    int pos = atomicAdd(&lc[cl], 1);
    if (pos < CAP) rtp[(nbase + cl) * CAP + pos] = (int)(e & 0xFFFFFu);
  }
  __syncthreads();
  int node = nbase + tid;
  if (node < NNODES) cnt[node] = lc[tid];
}

// ---------------------------------------------------------------------------
// k_nodeagg: one wave per node (unchanged except cnt indexing).
// ---------------------------------------------------------------------------
__global__ __launch_bounds__(256) void k_nodeagg(const int* __restrict__ cnt,
    const int* __restrict__ rtp, const float* __restrict__ h_l,
    const float* __restrict__ h_r, const float* __restrict__ he_t_g,
    const u16* __restrict__ emb, float* __restrict__ out){
  __shared__ float wl[4][CAP][4];      // [wave][slot][head], fp32
  __shared__ int   rl[4][CAP];

  const int wid = threadIdx.x >> 6;
  const int n = blockIdx.x * 4 + wid;            // grid*4 == NNODES exactly
  const int lane = threadIdx.x & 63;
  int deg = cnt[n]; if (deg > CAP) deg = CAP;
  const int base = n * CAP;

  // ---- prologue: per-slot weights, all slots in parallel ----
  {
    bool v = lane < deg;
    int rt = rtp[base + (v ? lane : 0)];
    int r = rt & 0x1FFFF, t = (rt >> 17) & 7;
    float4 hl = *(const float4*)&h_l[r * 4];
    float4 hr = *(const float4*)&h_r[n * 4];
    float4 he = *(const float4*)&he_t_g[t * 4];
    float x0 = hl.x + hr.x + he.x; x0 = x0 > 0.f ? x0 : NEG * x0;
    float x1 = hl.y + hr.y + he.y; x1 = x1 > 0.f ? x1 : NEG * x1;
    float x2 = hl.z + hr.z + he.z; x2 = x2 > 0.f ? x2 : NEG * x2;
    float x3 = hl.w + hr.w + he.w; x3 = x3 > 0.f ? x3 : NEG * x3;
    float4 w4 = make_float4(__expf(x0), __expf(x1), __expf(x2), __expf(x3));
    *(float4*)&wl[wid][lane][0] = w4;
    rl[wid][lane] = r;
  }
  __syncthreads();

  const int q = lane >> 4;             // quarter 0..3 -> edge i+q
  const int L = lane & 15;             // dims L*8 .. L*8+7 (emb layout [head][32])
  const int h = L >> 2;                // head of this lane's 8 dims

  float acc[8] = {0.f,0.f,0.f,0.f,0.f,0.f,0.f,0.f};
  float ds = 0.f;
  for (int i = 0; i < deg; i += 8){
    int i0 = i + q, i1 = i + 4 + q;
    bool v0 = i0 < deg, v1 = i1 < deg;
    int ii0 = v0 ? i0 : 0, ii1 = v1 ? i1 : 0;
    int r0 = rl[wid][ii0];                       // LDS broadcast
    int r1 = rl[wid][ii1];
    float w0 = v0 ? wl[wid][ii0][h] : 0.f;       // LDS broadcast
    float w1 = v1 ? wl[wid][ii1][h] : 0.f;
    ushort8 u0 = *(const ushort8*)&emb[r0 * 128 + L * 8];
    ushort8 u1 = *(const ushort8*)&emb[r1 * 128 + L * 8];
    #pragma unroll
    for (int k = 0; k < 8; ++k) acc[k] += w0 * bf2f((u16)u0[k]);
    ds += w0;
    #pragma unroll
    for (int k = 0; k < 8; ++k) acc[k] += w1 * bf2f((u16)u1[k]);
    ds += w1;
  }

  // combine the 4 quarters: lanes L, L+16, L+32, L+48 hold partials of same dims
  #pragma unroll
  for (int k = 0; k < 8; ++k){
    acc[k] += __shfl_xor(acc[k], 16, 64);
    acc[k] += __shfl_xor(acc[k], 32, 64);
  }
  ds += __shfl_xor(ds, 16, 64);
  ds += __shfl_xor(ds, 32, 64);

  if (q == 0){
    float inv = (deg > 0) ? 1.f / ds : 0.f;
    // dim j = L*8+k -> out offset n*128 + (j&31)*4 + head
    //              = n*128 + (L&3)*32 + k*4 + (L>>2)
    int ob = n * 128 + (L & 3) * 32 + (L >> 2);
    #pragma unroll
    for (int k = 0; k < 8; ++k){
      int o = ob + k * 4;
      float v = acc[k] * inv + out[o];
      out[o] = v > 0.f ? v : (__expf(v) - 1.f);
    }
  }
}

// ---------------------------------------------------------------------------
extern "C" void kernel_launch(void* const* d_in, const int* in_sizes, int n_in,
                              void* d_out, int out_size, void* d_ws, size_t ws_size,
                              hipStream_t stream){
  const float* hmat     = (const float*)d_in[0];
  const int*   row      = (const int*)d_in[1];
  const int*   col      = (const int*)d_in[2];
  const int*   et       = (const int*)d_in[3];
  const float* edge_emb = (const float*)d_in[4];
  const float* W        = (const float*)d_in[5];
  const float* Wr       = (const float*)d_in[6];
  const float* a_l      = (const float*)d_in[7];
  const float* a_r      = (const float*)d_in[8];
  const float* a_e      = (const float*)d_in[9];
  const float* res_w    = (const float*)d_in[10];
  const float* res_b    = (const float*)d_in[11];
  float* out = (float*)d_out;

  char* ws = (char*)d_ws;
  // he_t 256 | Wt 64K | h_l 1.6M | h_r 1.6M | cnt 400K | gcnt 1.6K |
  // seg 7.2M | rtp 25.6M | emb(bf16) 25.6M   (~62.1 MB)
  float* he_t   = (float*)(ws);
  u16*   Wt     = (u16*)  (ws + 256);
  float* h_l    = (float*)(ws + 65792);
  float* h_r    = (float*)(ws + 1665792);
  int*   cnt    = (int*)  (ws + 3265792);
  int*   gcnt   = (int*)  (ws + 3665792);
  u32*   seg    = (u32*)  (ws + 3667360);
  int*   rtp    = (int*)  (ws + 10892704);
  u16*   emb    = (u16*)  (ws + 36492704);

  hipLaunchKernelGGL(k_prep, dim3(129), dim3(256), 0, stream,
                     edge_emb, Wr, a_e, W, res_w, he_t, Wt, cnt, gcnt);
  hipLaunchKernelGGL(k_fusedA, dim3(PBLK + GB2), dim3(256), 0, stream,
                     hmat, Wt, res_b, a_l, a_r, emb, out, h_l, h_r,
                     row, col, et, gcnt, seg);
  hipLaunchKernelGGL(k_bucket, dim3(RB), dim3(256), 0, stream,
                     gcnt, seg, cnt, rtp);
  hipLaunchKernelGGL(k_nodeagg, dim3(NNODES / 4), dim3(256), 0, stream,
                     cnt, rtp, h_l, h_r, he_t, emb, out);
}

// Round 10
// 303.503 us; speedup vs baseline: 1.2683x; 1.0067x over previous
//
#include <hip/hip_runtime.h>

#define NNODES 100000
#define NEDGES 1600000
#define INDIM 128
#define OUTD 32
#define HEADS 4
#define EDIM 32
#define NET 8
#define NEG 0.2f
#define CAP 64           // per-node bucket capacity (Poisson(16): P(>64) ~ 1e-20)
#define RB 392           // coarse buckets: node >> 8, 392*256 = 100352 >= NNODES
#define SEGCAP 4608      // per-bucket segment cap (mean 4081, +8.2 sigma)
#define PBLK 196         // partition blocks, 8192 edges each (196*8192 >= NEDGES)
#define EPB 8192
#define GB2 782          // gemm blocks: ceil(100000/128)

typedef unsigned short u16;
typedef unsigned int u32;
typedef __attribute__((ext_vector_type(8))) short bf16x8;
typedef __attribute__((ext_vector_type(8))) unsigned short ushort8;
typedef __attribute__((ext_vector_type(4))) float f32x4;

__device__ __forceinline__ float bf2f(u16 u){ return __uint_as_float(((u32)u) << 16); }
__device__ __forceinline__ u16 f2bf(float f){
  u32 x = __float_as_uint(f);
  return (u16)((x + 0x7fffu + ((x >> 16) & 1u)) >> 16);   // RNE
}

// ---------------------------------------------------------------------------
// k_prep: zero cnt + gcnt; block 0 -> he_t; blocks 1..128 -> Wt transpose+cast
// ---------------------------------------------------------------------------
__global__ void k_prep(const float* __restrict__ edge_emb, const float* __restrict__ Wr,
                       const float* __restrict__ a_e, const float* __restrict__ W,
                       const float* __restrict__ res_w,
                       float* __restrict__ he_t, u16* __restrict__ Wt,
                       int* __restrict__ cnt, int* __restrict__ gcnt){
  const int b = blockIdx.x, tid = threadIdx.x;
  int4 z4 = make_int4(0, 0, 0, 0);
  for (int i = b * 256 + tid; i < NNODES / 4; i += gridDim.x * 256)
    ((int4*)cnt)[i] = z4;

  if (b == 0){
    for (int t = tid; t < RB; t += 256) gcnt[t] = 0;
    __shared__ float sc[NET * 128];
    for (int idx = tid; idx < NET * 128; idx += 256){
      int t = idx >> 7, o = idx & 127;
      float s = 0.f;
      #pragma unroll
      for (int e = 0; e < EDIM; ++e)
        s += edge_emb[t * EDIM + e] * Wr[t * EDIM * 128 + e * 128 + o];
      sc[idx] = s * a_e[o];
    }
    __syncthreads();
    if (tid < NET * HEADS){
      int t = tid >> 2, h = tid & 3;
      float s = 0.f;
      #pragma unroll
      for (int d = 0; d < EDIM; ++d) s += sc[t * 128 + h * EDIM + d];
      he_t[tid] = s;
    }
  } else {
    int idx = (b - 1) * 256 + tid;     // 128 blocks cover 256*128
    int n = idx >> 7, k = idx & 127;
    float v = (n < 128) ? W[k * 128 + n] : res_w[k * 128 + (n - 128)];
    Wt[idx] = f2bf(v);
  }
}

// ---------------------------------------------------------------------------
// k_fusedA: blocks [0,PBLK): edge partition into RB coarse buckets.
//   (LDS hist ranks -> one global atomic per (block,bucket) -> packed seg
//    writes; 77K global atomics vs 1.6M, confirmed win in round 9)
// blocks [PBLK,PBLK+GB2): MFMA GEMM (unchanged, measured).
// ---------------------------------------------------------------------------
__global__ __launch_bounds__(256) void k_fusedA(
    const float* __restrict__ hmat, const u16* __restrict__ Wt,
    const float* __restrict__ res_b, const float* __restrict__ a_l,
    const float* __restrict__ a_r, u16* __restrict__ emb, float* __restrict__ outres,
    float* __restrict__ h_l, float* __restrict__ h_r,
    const int* __restrict__ row, const int* __restrict__ col,
    const int* __restrict__ et, int* __restrict__ gcnt, u32* __restrict__ seg){
  __shared__ u16 rankL[EPB];           // 16 KB
  __shared__ int lcnt[RB];             // 1.57 KB
  __shared__ int gbaseL[RB];           // 1.57 KB
  const int tid = threadIdx.x;

  if (blockIdx.x < PBLK){              // ---- partition part ----
    for (int t = tid; t < RB; t += 256) lcnt[t] = 0;
    __syncthreads();
    const int base = blockIdx.x * EPB;
    // phase 1: strided coalesced int4 loads, LDS hist + local ranks
    #pragma unroll
    for (int j = 0; j < 8; ++j){
      int e0 = base + j * 1024 + tid * 4;
      if (e0 < NEDGES){
        int4 c4 = *(const int4*)&col[e0];
        int lp = j * 1024 + tid * 4;
        rankL[lp + 0] = (u16)atomicAdd(&lcnt[c4.x >> 8], 1);
        rankL[lp + 1] = (u16)atomicAdd(&lcnt[c4.y >> 8], 1);
        rankL[lp + 2] = (u16)atomicAdd(&lcnt[c4.z >> 8], 1);
        rankL[lp + 3] = (u16)atomicAdd(&lcnt[c4.w >> 8], 1);
      }
    }
    __syncthreads();
    // phase 2: reserve global segment space, one atomic per non-empty bucket
    for (int t = tid; t < RB; t += 256){
      int c = lcnt[t];
      gbaseL[t] = (c > 0) ? atomicAdd(&gcnt[t], c) : 0;
    }
    __syncthreads();
    // phase 3: write packed edges into segments (contiguous runs per bucket)
    #pragma unroll
    for (int j = 0; j < 8; ++j){
      int e0 = base + j * 1024 + tid * 4;
      if (e0 < NEDGES){
        int4 c4 = *(const int4*)&col[e0];
        int4 r4 = *(const int4*)&row[e0];
        int4 t4 = *(const int4*)&et[e0];
        int lp = j * 1024 + tid * 4;
        int b0 = c4.x >> 8, i0 = gbaseL[b0] + rankL[lp + 0];
        if (i0 < SEGCAP) seg[b0 * SEGCAP + i0] =
            (u32)r4.x | ((u32)t4.x << 17) | ((u32)(c4.x & 255) << 20);
        int b1 = c4.y >> 8, i1 = gbaseL[b1] + rankL[lp + 1];
        if (i1 < SEGCAP) seg[b1 * SEGCAP + i1] =
            (u32)r4.y | ((u32)t4.y << 17) | ((u32)(c4.y & 255) << 20);
        int b2 = c4.z >> 8, i2 = gbaseL[b2] + rankL[lp + 2];
        if (i2 < SEGCAP) seg[b2 * SEGCAP + i2] =
            (u32)r4.z | ((u32)t4.z << 17) | ((u32)(c4.z & 255) << 20);
        int b3 = c4.w >> 8, i3 = gbaseL[b3] + rankL[lp + 3];
        if (i3 < SEGCAP) seg[b3 * SEGCAP + i3] =
            (u32)r4.w | ((u32)t4.w << 17) | ((u32)(c4.w & 255) << 20);
      }
    }
    return;
  }

  // ---- GEMM part (no LDS use; B fragments straight from L2-resident Wt) ----
  const int gb = blockIdx.x - PBLK;
  const int wid = tid >> 6, lane = tid & 63;
  const int m0 = gb * 128 + wid * 32;
  const int mcol = lane & 15, quad = lane >> 4;

  bf16x8 A[2][4];
  #pragma unroll
  for (int mt = 0; mt < 2; ++mt){
    int r = m0 + mt * 16 + mcol;
    int rc = r < NNODES ? r : NNODES - 1;
    const float* hrow = &hmat[rc * 128 + quad * 8];
    #pragma unroll
    for (int ks = 0; ks < 4; ++ks){
      float4 a0 = *(const float4*)&hrow[ks * 32];
      float4 a1 = *(const float4*)&hrow[ks * 32 + 4];
      A[mt][ks][0] = (short)f2bf(a0.x); A[mt][ks][1] = (short)f2bf(a0.y);
      A[mt][ks][2] = (short)f2bf(a0.z); A[mt][ks][3] = (short)f2bf(a0.w);
      A[mt][ks][4] = (short)f2bf(a1.x); A[mt][ks][5] = (short)f2bf(a1.y);
      A[mt][ks][6] = (short)f2bf(a1.z); A[mt][ks][7] = (short)f2bf(a1.w);
    }
  }

  float pl[2][4] = {}, pr[2][4] = {};
  #pragma unroll
  for (int phase = 0; phase < 2; ++phase){
    #pragma unroll
    for (int ntl = 0; ntl < 8; ++ntl){
      bf16x8 B[4];
      const u16* bp = &Wt[(phase * 128 + ntl * 16 + mcol) * 128 + quad * 8];
      #pragma unroll
      for (int ks = 0; ks < 4; ++ks) B[ks] = *(const bf16x8*)&bp[ks * 32];

      f32x4 acc[2] = {{0.f,0.f,0.f,0.f},{0.f,0.f,0.f,0.f}};
      #pragma unroll
      for (int ks = 0; ks < 4; ++ks){
        acc[0] = __builtin_amdgcn_mfma_f32_16x16x32_bf16(A[0][ks], B[ks], acc[0], 0, 0, 0);
        acc[1] = __builtin_amdgcn_mfma_f32_16x16x32_bf16(A[1][ks], B[ks], acc[1], 0, 0, 0);
      }

      const int c = ntl * 16 + mcol;      // column within the 128-col phase
      if (phase == 0){
        float alc = a_l[c], arc = a_r[c];
        #pragma unroll
        for (int mt = 0; mt < 2; ++mt){
          #pragma unroll
          for (int reg = 0; reg < 4; ++reg){
            int rw = m0 + mt * 16 + quad * 4 + reg;
            if (rw < NNODES) emb[rw * 128 + c] = f2bf(acc[mt][reg]);
            pl[mt][reg] += alc * acc[mt][reg];
            pr[mt][reg] += arc * acc[mt][reg];
          }
        }
        if (ntl & 1){            // head h = ntl>>1 complete
          int h = ntl >> 1;
          #pragma unroll
          for (int mt = 0; mt < 2; ++mt){
            #pragma unroll
            for (int reg = 0; reg < 4; ++reg){
              float s0 = pl[mt][reg], s1 = pr[mt][reg];
              #pragma unroll
              for (int off = 1; off < 16; off <<= 1){
                s0 += __shfl_xor(s0, off, 64);
                s1 += __shfl_xor(s1, off, 64);
              }
              int rw = m0 + mt * 16 + quad * 4 + reg;
              if (mcol == 0 && rw < NNODES){
                h_l[rw * 4 + h] = s0;
                h_r[rw * 4 + h] = s1;
              }
              pl[mt][reg] = 0.f; pr[mt][reg] = 0.f;
            }
          }
        }
      } else {
        float rb = res_b[c];
        #pragma unroll
        for (int mt = 0; mt < 2; ++mt){
          #pragma unroll
          for (int reg = 0; reg < 4; ++reg){
            int rw = m0 + mt * 16 + quad * 4 + reg;
            if (rw < NNODES) outres[rw * 128 + c] = acc[mt][reg] + rb;
          }
        }
      }
    }
  }
}

// ---------------------------------------------------------------------------
// k_bucket: one block per coarse bucket (256 nodes). Replays the bucket's
// segment through 256 LDS counters -> exact rtp positions + cnt.
// ---------------------------------------------------------------------------
__global__ __launch_bounds__(256) void k_bucket(const int* __restrict__ gcnt,
    const u32* __restrict__ seg, int* __restrict__ cnt, int* __restrict__ rtp){
  __shared__ int lc[256];
  const int b = blockIdx.x;
  const int tid = threadIdx.x;
  lc[tid] = 0;
  __syncthreads();
  int m = gcnt[b]; if (m > SEGCAP) m = SEGCAP;
  const u32* s = &seg[b * SEGCAP];
  const int nbase = b << 8;
  for (int i = tid; i < m; i += 256){
    u32 e = s[i];
    int cl = e >> 20;
    int pos = atomicAdd(&lc[cl], 1);
    if (pos < CAP) rtp[(nbase + cl) * CAP + pos] = (int)(e & 0xFFFFFu);
  }
  __syncthreads();
  int node = nbase + tid;
  if (node < NNODES) cnt[node] = lc[tid];
}

// ---------------------------------------------------------------------------
// k_nodeagg: one wave per node.
// Main loop: quarter-wave per edge, UNROLL x4 -> 16 edges/iter, 4 independent
// dwordx4 gathers in flight per wave (was 2). VGPR was 20 -> ample headroom.
// ---------------------------------------------------------------------------
__global__ __launch_bounds__(256) void k_nodeagg(const int* __restrict__ cnt,
    const int* __restrict__ rtp, const float* __restrict__ h_l,
    const float* __restrict__ h_r, const float* __restrict__ he_t_g,
    const u16* __restrict__ emb, float* __restrict__ out){
  __shared__ float wl[4][CAP][4];      // [wave][slot][head], fp32
  __shared__ int   rl[4][CAP];

  const int wid = threadIdx.x >> 6;
  const int n = blockIdx.x * 4 + wid;            // grid*4 == NNODES exactly
  const int lane = threadIdx.x & 63;
  int deg = cnt[n]; if (deg > CAP) deg = CAP;
  const int base = n * CAP;

  // ---- prologue: per-slot weights, all slots in parallel ----
  {
    bool v = lane < deg;
    int rt = rtp[base + (v ? lane : 0)];
    int r = rt & 0x1FFFF, t = (rt >> 17) & 7;
    float4 hl = *(const float4*)&h_l[r * 4];
    float4 hr = *(const float4*)&h_r[n * 4];
    float4 he = *(const float4*)&he_t_g[t * 4];
    float x0 = hl.x + hr.x + he.x; x0 = x0 > 0.f ? x0 : NEG * x0;
    float x1 = hl.y + hr.y + he.y; x1 = x1 > 0.f ? x1 : NEG * x1;
    float x2 = hl.z + hr.z + he.z; x2 = x2 > 0.f ? x2 : NEG * x2;
    float x3 = hl.w + hr.w + he.w; x3 = x3 > 0.f ? x3 : NEG * x3;
    float4 w4 = make_float4(__expf(x0), __expf(x1), __expf(x2), __expf(x3));
    *(float4*)&wl[wid][lane][0] = w4;
    rl[wid][lane] = r;
  }
  __syncthreads();

  const int q = lane >> 4;             // quarter 0..3 -> edge i+q
  const int L = lane & 15;             // dims L*8 .. L*8+7 (emb layout [head][32])
  const int h = L >> 2;                // head of this lane's 8 dims

  float acc[8] = {0.f,0.f,0.f,0.f,0.f,0.f,0.f,0.f};
  float ds = 0.f;
  for (int i = 0; i < deg; i += 16){
    int i0 = i + q, i1 = i + 4 + q, i2 = i + 8 + q, i3 = i + 12 + q;
    bool v0 = i0 < deg, v1 = i1 < deg, v2 = i2 < deg, v3 = i3 < deg;
    int ii0 = v0 ? i0 : 0, ii1 = v1 ? i1 : 0;
    int ii2 = v2 ? i2 : 0, ii3 = v3 ? i3 : 0;
    int r0 = rl[wid][ii0];                       // LDS broadcasts
    int r1 = rl[wid][ii1];
    int r2 = rl[wid][ii2];
    int r3 = rl[wid][ii3];
    float w0 = v0 ? wl[wid][ii0][h] : 0.f;
    float w1 = v1 ? wl[wid][ii1][h] : 0.f;
    float w2 = v2 ? wl[wid][ii2][h] : 0.f;
    float w3 = v3 ? wl[wid][ii3][h] : 0.f;
    ushort8 u0 = *(const ushort8*)&emb[r0 * 128 + L * 8];   // 4 independent
    ushort8 u1 = *(const ushort8*)&emb[r1 * 128 + L * 8];   // gathers in
    ushort8 u2 = *(const ushort8*)&emb[r2 * 128 + L * 8];   // flight
    ushort8 u3 = *(const ushort8*)&emb[r3 * 128 + L * 8];
    #pragma unroll
    for (int k = 0; k < 8; ++k) acc[k] += w0 * bf2f((u16)u0[k]);
    ds += w0;
    #pragma unroll
    for (int k = 0; k < 8; ++k) acc[k] += w1 * bf2f((u16)u1[k]);
    ds += w1;
    #pragma unroll
    for (int k = 0; k < 8; ++k) acc[k] += w2 * bf2f((u16)u2[k]);
    ds += w2;
    #pragma unroll
    for (int k = 0; k < 8; ++k) acc[k] += w3 * bf2f((u16)u3[k]);
    ds += w3;
  }

  // combine the 4 quarters: lanes L, L+16, L+32, L+48 hold partials of same dims
  #pragma unroll
  for (int k = 0; k < 8; ++k){
    acc[k] += __shfl_xor(acc[k], 16, 64);
    acc[k] += __shfl_xor(acc[k], 32, 64);
  }
  ds += __shfl_xor(ds, 16, 64);
  ds += __shfl_xor(ds, 32, 64);

  if (q == 0){
    float inv = (deg > 0) ? 1.f / ds : 0.f;
    // dim j = L*8+k -> out offset n*128 + (j&31)*4 + head
    //              = n*128 + (L&3)*32 + k*4 + (L>>2)
    int ob = n * 128 + (L & 3) * 32 + (L >> 2);
    #pragma unroll
    for (int k = 0; k < 8; ++k){
      int o = ob + k * 4;
      float v = acc[k] * inv + out[o];
      out[o] = v > 0.f ? v : (__expf(v) - 1.f);
    }
  }
}

// ---------------------------------------------------------------------------
extern "C" void kernel_launch(void* const* d_in, const int* in_sizes, int n_in,
                              void* d_out, int out_size, void* d_ws, size_t ws_size,
                              hipStream_t stream){
  const float* hmat     = (const float*)d_in[0];
  const int*   row      = (const int*)d_in[1];
  const int*   col      = (const int*)d_in[2];
  const int*   et       = (const int*)d_in[3];
  const float* edge_emb = (const float*)d_in[4];
  const float* W        = (const float*)d_in[5];
  const float* Wr       = (const float*)d_in[6];
  const float* a_l      = (const float*)d_in[7];
  const float* a_r      = (const float*)d_in[8];
  const float* a_e      = (const float*)d_in[9];
  const float* res_w    = (const float*)d_in[10];
  const float* res_b    = (const float*)d_in[11];
  float* out = (float*)d_out;

  char* ws = (char*)d_ws;
  // he_t 256 | Wt 64K | h_l 1.6M | h_r 1.6M | cnt 400K | gcnt 1.6K |
  // seg 7.2M | rtp 25.6M | emb(bf16) 25.6M   (~62.1 MB)
  float* he_t   = (float*)(ws);
  u16*   Wt     = (u16*)  (ws + 256);
  float* h_l    = (float*)(ws + 65792);
  float* h_r    = (float*)(ws + 1665792);
  int*   cnt    = (int*)  (ws + 3265792);
  int*   gcnt   = (int*)  (ws + 3665792);
  u32*   seg    = (u32*)  (ws + 3667360);
  int*   rtp    = (int*)  (ws + 10892704);
  u16*   emb    = (u16*)  (ws + 36492704);

  hipLaunchKernelGGL(k_prep, dim3(129), dim3(256), 0, stream,
                     edge_emb, Wr, a_e, W, res_w, he_t, Wt, cnt, gcnt);
  hipLaunchKernelGGL(k_fusedA, dim3(PBLK + GB2), dim3(256), 0, stream,
                     hmat, Wt, res_b, a_l, a_r, emb, out, h_l, h_r,
                     row, col, et, gcnt, seg);
  hipLaunchKernelGGL(k_bucket, dim3(RB), dim3(256), 0, stream,
                     gcnt, seg, cnt, rtp);
  hipLaunchKernelGGL(k_nodeagg, dim3(NNODES / 4), dim3(256), 0, stream,
                     cnt, rtp, h_l, h_r, he_t, emb, out);
}